// Round 2
// baseline (315.660 us; speedup 1.0000x reference)
//
#include <hip/hip_runtime.h>
#include <hip/hip_bf16.h>

#define Tq 4096
#define Cdim 1024
#define NH 16
#define DH 64

typedef __attribute__((ext_vector_type(8))) short short8;
typedef __attribute__((ext_vector_type(4))) float f32x4;

__device__ __forceinline__ unsigned short f2bf(float f) {
  union { float f; unsigned int u; } v; v.f = f;
  unsigned int r = v.u + 0x7FFFu + ((v.u >> 16) & 1u);
  return (unsigned short)(r >> 16);
}

// ---------------- fp32 -> bf16 convert ----------------
__global__ void cvt_kernel(const float* __restrict__ in, unsigned short* __restrict__ out, int n) {
  int idx = (blockIdx.x * blockDim.x + threadIdx.x) * 4;
  if (idx + 3 < n) {
    float4 v = *reinterpret_cast<const float4*>(in + idx);
    ushort4 o;
    o.x = f2bf(v.x); o.y = f2bf(v.y); o.z = f2bf(v.z); o.w = f2bf(v.w);
    *reinterpret_cast<ushort4*>(out + idx) = o;
  }
}

// ------------- transpose + convert: in[R][C] f32 -> out[C][R] bf16 -------------
__global__ void transpose_cvt(const float* __restrict__ in, unsigned short* __restrict__ out,
                              int R, int Ccols) {
  __shared__ float tile[64][65];
  int c0 = blockIdx.x * 64, r0 = blockIdx.y * 64;
  int tx = threadIdx.x & 63;
  int ty = threadIdx.x >> 6;   // 0..3
  #pragma unroll
  for (int rr = 0; rr < 64; rr += 4)
    tile[rr + ty][tx] = in[(r0 + rr + ty) * Ccols + c0 + tx];
  __syncthreads();
  #pragma unroll
  for (int rr = 0; rr < 64; rr += 4)
    out[(c0 + rr + ty) * R + r0 + tx] = f2bf(tile[tx][rr + ty]);
}

// ------------- GEMM: C[M][N] = A[M][K](bf16) * B^T[N][K](bf16) -------------
// OUT_MODE 0: scatter bf16 into qkv buffer: Q[h][t][d], K[h][t][d], VT[h][d][t]
// OUT_MODE 1: fp32 row-major [M][N]
template<int OUT_MODE>
__global__ __launch_bounds__(256, 2)
void gemm_bt(const unsigned short* __restrict__ A,
             const unsigned short* __restrict__ B,
             void* __restrict__ Cout,
             int M, int N, int K)
{
  __shared__ __align__(16) unsigned short As[128][72];
  __shared__ __align__(16) unsigned short Bs[128][72];
  const int tid = threadIdx.x;
  const int lane = tid & 63;
  const int wave = tid >> 6;
  const int wm = wave >> 1, wn = wave & 1;
  const int m0 = blockIdx.y * 128, n0 = blockIdx.x * 128;

  f32x4 acc[4][4] = {};

  const int srow = tid >> 3;          // 0..31
  const int scol = (tid & 7) * 8;     // element col

  for (int k0 = 0; k0 < K; k0 += 64) {
    __syncthreads();
    #pragma unroll
    for (int r = 0; r < 128; r += 32) {
      *reinterpret_cast<short8*>(&As[srow + r][scol]) =
        *reinterpret_cast<const short8*>(&A[(m0 + srow + r) * K + k0 + scol]);
      *reinterpret_cast<short8*>(&Bs[srow + r][scol]) =
        *reinterpret_cast<const short8*>(&B[(n0 + srow + r) * K + k0 + scol]);
    }
    __syncthreads();
    #pragma unroll
    for (int kk = 0; kk < 64; kk += 32) {
      const int frow = lane & 15;
      const int fcol = kk + 8 * (lane >> 4);
      short8 a[4], b[4];
      #pragma unroll
      for (int i = 0; i < 4; ++i) {
        a[i] = *reinterpret_cast<const short8*>(&As[wm * 64 + i * 16 + frow][fcol]);
        b[i] = *reinterpret_cast<const short8*>(&Bs[wn * 64 + i * 16 + frow][fcol]);
      }
      #pragma unroll
      for (int i = 0; i < 4; ++i)
        #pragma unroll
        for (int j = 0; j < 4; ++j)
          acc[i][j] = __builtin_amdgcn_mfma_f32_16x16x32_bf16(a[i], b[j], acc[i][j], 0, 0, 0);
    }
  }

  const int rbase = (lane >> 4) * 4;
  const int ccol = lane & 15;
  #pragma unroll
  for (int i = 0; i < 4; ++i) {
    const int row0 = m0 + wm * 64 + i * 16 + rbase;
    #pragma unroll
    for (int j = 0; j < 4; ++j) {
      const int col = n0 + wn * 64 + j * 16 + ccol;
      if (OUT_MODE == 0) {
        unsigned short* q = (unsigned short*)Cout;
        int sec = col >> 10, rem = col & 1023;
        int hh = rem >> 6, d = rem & 63;
        if (sec == 2) {
          // V stored transposed: VT[h][d][t]; 4 consecutive t -> one 8B store
          ushort4 pk;
          pk.x = f2bf(acc[i][j][0]); pk.y = f2bf(acc[i][j][1]);
          pk.z = f2bf(acc[i][j][2]); pk.w = f2bf(acc[i][j][3]);
          *reinterpret_cast<ushort4*>(
              &q[((size_t)(2 * NH + hh) * DH + d) * Tq + row0]) = pk;
        } else {
          #pragma unroll
          for (int r = 0; r < 4; ++r)
            q[(((size_t)sec * NH + hh) * Tq + row0 + r) * DH + d] = f2bf(acc[i][j][r]);
        }
      } else {
        #pragma unroll
        for (int r = 0; r < 4; ++r)
          ((float*)Cout)[(row0 + r) * N + col] = acc[i][j][r];
      }
    }
  }
}

// ------------- flash attention: causal + dense prefix -------------
#define PS_STRIDE 76   // 38 dwords: 4-row bank offsets {0,24,16,8} -> conflict-free

__global__ __launch_bounds__(256, 4)
void attn_kernel(const unsigned short* __restrict__ qkv,   // Q[h][t][d],K[h][t][d],VT[h][d][t]
                 unsigned short* __restrict__ y,           // [Tq][Cdim] bf16
                 const int* __restrict__ nf_ptr)
{
  __shared__ __align__(16) unsigned short Ks[64][72];
  __shared__ __align__(16) unsigned short VTs[64][72];
  __shared__ __align__(16) unsigned short Ps[4][16][PS_STRIDE];

  const int tid = threadIdx.x;
  const int lane = tid & 63;
  const int w = tid >> 6;
  const int h = blockIdx.x & (NH - 1);
  const int b = blockIdx.x >> 4;
  // pair heavy/light blocks so co-resident sets are balanced
  const int qt = (b & 1) ? (b >> 1) : (Tq / 64 - 1 - (b >> 1));
  const int q0 = qt * 64;
  const int nf = nf_ptr[0];

  const unsigned short* Qh  = qkv + (size_t)(h * Tq) * DH;
  const unsigned short* Kh  = qkv + (size_t)((NH + h) * Tq) * DH;
  const unsigned short* VTh = qkv + ((size_t)(2 * NH + h) * DH) * Tq;

  // Q fragments hoisted to registers
  const int qrow_a = q0 + w * 16 + (lane & 15);
  short8 qf[2];
  #pragma unroll
  for (int kk = 0; kk < 2; ++kk)
    qf[kk] = *reinterpret_cast<const short8*>(&Qh[qrow_a * DH + kk * 32 + 8 * (lane >> 4)]);

  float m_r[4], l_r[4];
  f32x4 o[4] = {};
  #pragma unroll
  for (int r = 0; r < 4; ++r) { m_r[r] = -1e30f; l_r[r] = 0.f; }

  int lastt = q0 + 63;
  if (nf - 1 > lastt) lastt = nf - 1;
  const int ktend = lastt >> 6;

  const float SCL = 0.125f * 1.44269504f;   // 1/sqrt(64) * log2(e)

  const int rr = tid >> 3;          // 0..31
  const int sc = (tid & 7) * 8;

  for (int kt = 0; kt <= ktend; ++kt) {
    const int kv0 = kt * 64;
    __syncthreads();
    // stage K rows (vectorized)
    *reinterpret_cast<short8*>(&Ks[rr][sc]) =
      *reinterpret_cast<const short8*>(&Kh[(kv0 + rr) * DH + sc]);
    *reinterpret_cast<short8*>(&Ks[rr + 32][sc]) =
      *reinterpret_cast<const short8*>(&Kh[(kv0 + rr + 32) * DH + sc]);
    // stage V^T rows (vectorized — V is pre-transposed in global)
    *reinterpret_cast<short8*>(&VTs[rr][sc]) =
      *reinterpret_cast<const short8*>(&VTh[rr * Tq + kv0 + sc]);
    *reinterpret_cast<short8*>(&VTs[rr + 32][sc]) =
      *reinterpret_cast<const short8*>(&VTh[(rr + 32) * Tq + kv0 + sc]);
    __syncthreads();

    // S = Q K^T (in exp2 domain units)
    f32x4 s[4];
    #pragma unroll
    for (int nb = 0; nb < 4; ++nb) {
      f32x4 a = {};
      #pragma unroll
      for (int kk = 0; kk < 2; ++kk) {
        short8 kf = *reinterpret_cast<const short8*>(
            &Ks[nb * 16 + (lane & 15)][kk * 32 + 8 * (lane >> 4)]);
        a = __builtin_amdgcn_mfma_f32_16x16x32_bf16(qf[kk], kf, a, 0, 0, 0);
      }
      s[nb] = a;
    }

    const int rowb = q0 + w * 16 + (lane >> 4) * 4;
    const bool needmask = !((kv0 + 63 <= q0 + w * 16) || (kv0 + 63 < nf));
    #pragma unroll
    for (int nb = 0; nb < 4; ++nb) {
      const int col = kv0 + nb * 16 + (lane & 15);
      #pragma unroll
      for (int r = 0; r < 4; ++r) {
        float v = s[nb][r] * SCL;
        if (needmask && !(col <= rowb + r || col < nf)) v = -1e30f;
        s[nb][r] = v;
      }
    }

    // online softmax (row stats across 16-lane groups), exp2 domain
    float vmax[4];
    #pragma unroll
    for (int r = 0; r < 4; ++r) {
      float v = fmaxf(fmaxf(s[0][r], s[1][r]), fmaxf(s[2][r], s[3][r]));
      #pragma unroll
      for (int off = 8; off >= 1; off >>= 1)
        v = fmaxf(v, __shfl_xor(v, off, 64));
      vmax[r] = v;
    }
    float alpha[4];
    #pragma unroll
    for (int r = 0; r < 4; ++r) {
      float mn = fmaxf(m_r[r], vmax[r]);
      alpha[r] = exp2f(m_r[r] - mn);
      m_r[r] = mn;
    }
    float rs[4] = {0.f, 0.f, 0.f, 0.f};
    #pragma unroll
    for (int nb = 0; nb < 4; ++nb) {
      #pragma unroll
      for (int r = 0; r < 4; ++r) {
        float p = exp2f(s[nb][r] - m_r[r]);
        rs[r] += p;
        Ps[w][(lane >> 4) * 4 + r][nb * 16 + (lane & 15)] = f2bf(p);
      }
    }
    #pragma unroll
    for (int r = 0; r < 4; ++r) {
      float v = rs[r];
      #pragma unroll
      for (int off = 8; off >= 1; off >>= 1)
        v += __shfl_xor(v, off, 64);
      l_r[r] = l_r[r] * alpha[r] + v;
    }
    #pragma unroll
    for (int db = 0; db < 4; ++db)
      #pragma unroll
      for (int r = 0; r < 4; ++r)
        o[db][r] *= alpha[r];

    __syncthreads();

    // O += P * V    (B-fragments from V^T tile)
    #pragma unroll
    for (int kk = 0; kk < 2; ++kk) {
      short8 pa = *reinterpret_cast<const short8*>(
          &Ps[w][lane & 15][kk * 32 + 8 * (lane >> 4)]);
      #pragma unroll
      for (int db = 0; db < 4; ++db) {
        short8 vb = *reinterpret_cast<const short8*>(
            &VTs[db * 16 + (lane & 15)][kk * 32 + 8 * (lane >> 4)]);
        o[db] = __builtin_amdgcn_mfma_f32_16x16x32_bf16(pa, vb, o[db], 0, 0, 0);
      }
    }
  }

  // epilogue: y[t][h*64+d]
  const int orow = q0 + w * 16 + (lane >> 4) * 4;
  const int ocol = h * DH + (lane & 15);
  #pragma unroll
  for (int db = 0; db < 4; ++db) {
    #pragma unroll
    for (int r = 0; r < 4; ++r) {
      float v = o[db][r] / l_r[r];
      y[(orow + r) * Cdim + ocol + db * 16] = f2bf(v);
    }
  }
}

extern "C" void kernel_launch(void* const* d_in, const int* in_sizes, int n_in,
                              void* d_out, int out_size, void* d_ws, size_t ws_size,
                              hipStream_t stream) {
  (void)in_sizes; (void)n_in; (void)out_size; (void)ws_size;
  const float* x  = (const float*)d_in[0];
  const float* wa = (const float*)d_in[1];
  const float* wp = (const float*)d_in[2];
  const int*   nf = (const int*)d_in[3];
  float* out = (float*)d_out;

  char* ws = (char*)d_ws;
  unsigned short* x_bf = (unsigned short*)(ws);                              // 8 MiB
  unsigned short* waT  = (unsigned short*)(ws + (size_t)8  * 1024 * 1024);   // 6 MiB
  unsigned short* wpT  = (unsigned short*)(ws + (size_t)14 * 1024 * 1024);   // 2 MiB
  unsigned short* qkvb = (unsigned short*)(ws + (size_t)16 * 1024 * 1024);   // 24 MiB
  unsigned short* ybf  = (unsigned short*)(ws + (size_t)40 * 1024 * 1024);   // 8 MiB

  cvt_kernel<<<4096, 256, 0, stream>>>(x, x_bf, Tq * Cdim);
  transpose_cvt<<<dim3(48, 16), 256, 0, stream>>>(wa, waT, 1024, 3072);
  transpose_cvt<<<dim3(16, 16), 256, 0, stream>>>(wp, wpT, 1024, 1024);
  gemm_bt<0><<<dim3(24, 32), 256, 0, stream>>>(x_bf, waT, (void*)qkvb, Tq, 3 * Cdim, Cdim);
  attn_kernel<<<NH * (Tq / 64), 256, 0, stream>>>(qkvb, ybf, nf);
  gemm_bt<1><<<dim3(Cdim / 128, Tq / 128), 256, 0, stream>>>(ybf, wpT, (void*)out, Tq, Cdim, Cdim);
}

// Round 3
// 299.169 us; speedup vs baseline: 1.0551x; 1.0551x over previous
//
#include <hip/hip_runtime.h>
#include <hip/hip_bf16.h>

#define Tq 4096
#define Cdim 1024
#define NH 16
#define DH 64

typedef __attribute__((ext_vector_type(8))) short short8;
typedef __attribute__((ext_vector_type(4))) float f32x4;

__device__ __forceinline__ unsigned short f2bf(float f) {
  union { float f; unsigned int u; } v; v.f = f;
  unsigned int r = v.u + 0x7FFFu + ((v.u >> 16) & 1u);
  return (unsigned short)(r >> 16);
}

// ---------------- fp32 -> bf16 convert ----------------
__global__ void cvt_kernel(const float* __restrict__ in, unsigned short* __restrict__ out, int n) {
  int idx = (blockIdx.x * blockDim.x + threadIdx.x) * 4;
  if (idx + 3 < n) {
    float4 v = *reinterpret_cast<const float4*>(in + idx);
    ushort4 o;
    o.x = f2bf(v.x); o.y = f2bf(v.y); o.z = f2bf(v.z); o.w = f2bf(v.w);
    *reinterpret_cast<ushort4*>(out + idx) = o;
  }
}

// ------------- transpose + convert: in[R][C] f32 -> out[C][R] bf16 -------------
__global__ void transpose_cvt(const float* __restrict__ in, unsigned short* __restrict__ out,
                              int R, int Ccols) {
  __shared__ float tile[64][65];
  int c0 = blockIdx.x * 64, r0 = blockIdx.y * 64;
  int tx = threadIdx.x & 63;
  int ty = threadIdx.x >> 6;   // 0..3
  #pragma unroll
  for (int rr = 0; rr < 64; rr += 4)
    tile[rr + ty][tx] = in[(r0 + rr + ty) * Ccols + c0 + tx];
  __syncthreads();
  #pragma unroll
  for (int rr = 0; rr < 64; rr += 4)
    out[(c0 + rr + ty) * R + r0 + tx] = f2bf(tile[tx][rr + ty]);
}

// ------------- GEMM: C[M][N] = A[M][K](bf16) * B^T[N][K](bf16) -------------
// OUT_MODE 0: scatter bf16 into qkv buffer: Q[h][t][d], K[h][t][d], VT[h][d][t]
// OUT_MODE 1: fp32 row-major [M][N]
template<int OUT_MODE>
__global__ __launch_bounds__(256, 2)
void gemm_bt(const unsigned short* __restrict__ A,
             const unsigned short* __restrict__ B,
             void* __restrict__ Cout,
             int M, int N, int K)
{
  __shared__ __align__(16) unsigned short As[128][72];
  __shared__ __align__(16) unsigned short Bs[128][72];
  const int tid = threadIdx.x;
  const int lane = tid & 63;
  const int wave = tid >> 6;
  const int wm = wave >> 1, wn = wave & 1;
  const int m0 = blockIdx.y * 128, n0 = blockIdx.x * 128;

  f32x4 acc[4][4] = {};

  const int srow = tid >> 3;          // 0..31
  const int scol = (tid & 7) * 8;     // element col

  for (int k0 = 0; k0 < K; k0 += 64) {
    __syncthreads();
    #pragma unroll
    for (int r = 0; r < 128; r += 32) {
      *reinterpret_cast<short8*>(&As[srow + r][scol]) =
        *reinterpret_cast<const short8*>(&A[(m0 + srow + r) * K + k0 + scol]);
      *reinterpret_cast<short8*>(&Bs[srow + r][scol]) =
        *reinterpret_cast<const short8*>(&B[(n0 + srow + r) * K + k0 + scol]);
    }
    __syncthreads();
    #pragma unroll
    for (int kk = 0; kk < 64; kk += 32) {
      const int frow = lane & 15;
      const int fcol = kk + 8 * (lane >> 4);
      short8 a[4], b[4];
      #pragma unroll
      for (int i = 0; i < 4; ++i) {
        a[i] = *reinterpret_cast<const short8*>(&As[wm * 64 + i * 16 + frow][fcol]);
        b[i] = *reinterpret_cast<const short8*>(&Bs[wn * 64 + i * 16 + frow][fcol]);
      }
      #pragma unroll
      for (int i = 0; i < 4; ++i)
        #pragma unroll
        for (int j = 0; j < 4; ++j)
          acc[i][j] = __builtin_amdgcn_mfma_f32_16x16x32_bf16(a[i], b[j], acc[i][j], 0, 0, 0);
    }
  }

  const int rbase = (lane >> 4) * 4;
  const int ccol = lane & 15;
  #pragma unroll
  for (int i = 0; i < 4; ++i) {
    const int row0 = m0 + wm * 64 + i * 16 + rbase;
    #pragma unroll
    for (int j = 0; j < 4; ++j) {
      const int col = n0 + wn * 64 + j * 16 + ccol;
      if (OUT_MODE == 0) {
        unsigned short* q = (unsigned short*)Cout;
        int sec = col >> 10, rem = col & 1023;
        int hh = rem >> 6, d = rem & 63;
        if (sec == 2) {
          // V stored transposed: VT[h][d][t]; 4 consecutive t -> one 8B store
          ushort4 pk;
          pk.x = f2bf(acc[i][j][0]); pk.y = f2bf(acc[i][j][1]);
          pk.z = f2bf(acc[i][j][2]); pk.w = f2bf(acc[i][j][3]);
          *reinterpret_cast<ushort4*>(
              &q[((size_t)(2 * NH + hh) * DH + d) * Tq + row0]) = pk;
        } else {
          #pragma unroll
          for (int r = 0; r < 4; ++r)
            q[(((size_t)sec * NH + hh) * Tq + row0 + r) * DH + d] = f2bf(acc[i][j][r]);
        }
      } else {
        #pragma unroll
        for (int r = 0; r < 4; ++r)
          ((float*)Cout)[(row0 + r) * N + col] = acc[i][j][r];
      }
    }
  }
}

// ------------- flash attention: causal + dense prefix -------------
// QBLK=128 (4 waves x 32 rows), KVBLK=64, double-buffered K/V, 1 barrier/tile.
#define PS_STRIDE 76   // 38 dwords: 4-row bank offsets {0,24,16,8} -> conflict-free

__global__ __launch_bounds__(256, 2)
void attn_kernel(const unsigned short* __restrict__ qkv,   // Q[h][t][d],K[h][t][d],VT[h][d][t]
                 unsigned short* __restrict__ y,           // [Tq][Cdim] bf16
                 const int* __restrict__ nf_ptr)
{
  __shared__ __align__(16) unsigned short Ks[2][64][72];
  __shared__ __align__(16) unsigned short VTs[2][64][72];
  __shared__ __align__(16) unsigned short Ps[4][32][PS_STRIDE];

  const int tid  = threadIdx.x;
  const int lane = tid & 63;
  const int w    = tid >> 6;
  // dispatch-robust heavy/light pairing on bit 8: under round-robin a CU
  // gets {c, c+256} = same head, chunks qc and 31-qc (constant total work).
  const int lo = blockIdx.x & 255;
  const int hi = blockIdx.x >> 8;
  const int h  = lo & 15;
  const int iq = lo >> 4;                  // 0..15
  const int qc = hi ? iq : (31 - iq);      // 0..31
  const int q0 = qc * 128;
  const int nf = nf_ptr[0];

  const unsigned short* Qh  = qkv + (size_t)h * Tq * DH;
  const unsigned short* Kh  = qkv + (size_t)(NH + h) * Tq * DH;
  const unsigned short* VTh = qkv + (size_t)(2 * NH + h) * DH * Tq;

  const int g  = lane >> 4;       // 0..3
  const int li = lane & 15;

  // Q fragments (two 16-row groups per wave) hoisted to registers
  short8 qf[2][2];
  #pragma unroll
  for (int r0 = 0; r0 < 2; ++r0)
    #pragma unroll
    for (int kk = 0; kk < 2; ++kk)
      qf[r0][kk] = *reinterpret_cast<const short8*>(
          &Qh[(q0 + w * 32 + r0 * 16 + li) * DH + kk * 32 + 8 * g]);

  f32x4 o[2][4] = {};
  f32x4 ol[2] = {};               // row-sum accumulators (via ones-MFMA)
  float m_r[2][4];
  #pragma unroll
  for (int r0 = 0; r0 < 2; ++r0)
    #pragma unroll
    for (int r = 0; r < 4; ++r) m_r[r0][r] = -1e30f;

  short8 ones;
  #pragma unroll
  for (int e = 0; e < 8; ++e) ones[e] = (short)0x3F80;   // bf16 1.0

  int lastt = q0 + 127;
  if (nf - 1 > lastt) lastt = nf - 1;
  const int ktend = lastt >> 6;

  const float SCL = 0.125f * 1.44269504f;   // 1/sqrt(64) * log2(e)

  const int rr = tid >> 3;          // 0..31
  const int sc = (tid & 7) * 8;

  // prologue: stage tile 0 into buffer 0
  {
    short8 a0 = *reinterpret_cast<const short8*>(&Kh[rr * DH + sc]);
    short8 a1 = *reinterpret_cast<const short8*>(&Kh[(rr + 32) * DH + sc]);
    short8 b0 = *reinterpret_cast<const short8*>(&VTh[rr * Tq + sc]);
    short8 b1 = *reinterpret_cast<const short8*>(&VTh[(rr + 32) * Tq + sc]);
    *reinterpret_cast<short8*>(&Ks[0][rr][sc]) = a0;
    *reinterpret_cast<short8*>(&Ks[0][rr + 32][sc]) = a1;
    *reinterpret_cast<short8*>(&VTs[0][rr][sc]) = b0;
    *reinterpret_cast<short8*>(&VTs[0][rr + 32][sc]) = b1;
  }
  __syncthreads();

  int cur = 0;
  for (int kt = 0; kt <= ktend; ++kt) {
    const int kv0 = kt * 64;
    const bool havenext = (kt < ktend);
    // async-stage: issue next tile's global loads now, write to LDS after compute
    short8 nk0, nk1, nv0, nv1;
    if (havenext) {
      const int nx = kv0 + 64;
      nk0 = *reinterpret_cast<const short8*>(&Kh[(nx + rr) * DH + sc]);
      nk1 = *reinterpret_cast<const short8*>(&Kh[(nx + rr + 32) * DH + sc]);
      nv0 = *reinterpret_cast<const short8*>(&VTh[rr * Tq + nx + sc]);
      nv1 = *reinterpret_cast<const short8*>(&VTh[(rr + 32) * Tq + nx + sc]);
    }

    // K fragments (shared across both row groups)
    short8 kf[4][2];
    #pragma unroll
    for (int nb = 0; nb < 4; ++nb)
      #pragma unroll
      for (int kk = 0; kk < 2; ++kk)
        kf[nb][kk] = *reinterpret_cast<const short8*>(
            &Ks[cur][nb * 16 + li][kk * 32 + 8 * g]);

    #pragma unroll
    for (int r0 = 0; r0 < 2; ++r0) {
      // S = Q K^T
      f32x4 s[4];
      #pragma unroll
      for (int nb = 0; nb < 4; ++nb) {
        f32x4 a = {};
        #pragma unroll
        for (int kk = 0; kk < 2; ++kk)
          a = __builtin_amdgcn_mfma_f32_16x16x32_bf16(qf[r0][kk], kf[nb][kk], a, 0, 0, 0);
        s[nb] = a;
      }

      const int rowb = q0 + w * 32 + r0 * 16 + g * 4;
      const bool needmask = !((kv0 + 63 <= q0 + w * 32 + r0 * 16) || (kv0 + 63 < nf));
      #pragma unroll
      for (int nb = 0; nb < 4; ++nb) {
        const int col = kv0 + nb * 16 + li;
        #pragma unroll
        for (int r = 0; r < 4; ++r) {
          float v = s[nb][r] * SCL;
          if (needmask && !(col <= rowb + r || col < nf)) v = -1e30f;
          s[nb][r] = v;
        }
      }

      // row max (only remaining shuffle chain)
      float alpha[4];
      #pragma unroll
      for (int r = 0; r < 4; ++r) {
        float v = fmaxf(fmaxf(s[0][r], s[1][r]), fmaxf(s[2][r], s[3][r]));
        #pragma unroll
        for (int off = 8; off >= 1; off >>= 1)
          v = fmaxf(v, __shfl_xor(v, off, 64));
        float mn = fmaxf(m_r[r0][r], v);
        alpha[r] = exp2f(m_r[r0][r] - mn);
        m_r[r0][r] = mn;
      }
      // P = exp2(S - m), store bf16 to per-wave LDS
      #pragma unroll
      for (int nb = 0; nb < 4; ++nb) {
        #pragma unroll
        for (int r = 0; r < 4; ++r) {
          float p = exp2f(s[nb][r] - m_r[r0][r]);
          Ps[w][r0 * 16 + g * 4 + r][nb * 16 + li] = f2bf(p);
        }
      }
      // rescale accumulators
      #pragma unroll
      for (int db = 0; db < 4; ++db)
        #pragma unroll
        for (int r = 0; r < 4; ++r)
          o[r0][db][r] *= alpha[r];
      #pragma unroll
      for (int r = 0; r < 4; ++r)
        ol[r0][r] *= alpha[r];
    }

    // V fragments (shared across row groups)
    short8 vb[4][2];
    #pragma unroll
    for (int db = 0; db < 4; ++db)
      #pragma unroll
      for (int kk = 0; kk < 2; ++kk)
        vb[db][kk] = *reinterpret_cast<const short8*>(
            &VTs[cur][db * 16 + li][kk * 32 + 8 * g]);

    #pragma unroll
    for (int r0 = 0; r0 < 2; ++r0) {
      short8 pa[2];
      #pragma unroll
      for (int kk = 0; kk < 2; ++kk)
        pa[kk] = *reinterpret_cast<const short8*>(
            &Ps[w][r0 * 16 + li][kk * 32 + 8 * g]);
      #pragma unroll
      for (int kk = 0; kk < 2; ++kk) {
        #pragma unroll
        for (int db = 0; db < 4; ++db)
          o[r0][db] = __builtin_amdgcn_mfma_f32_16x16x32_bf16(pa[kk], vb[db][kk], o[r0][db], 0, 0, 0);
        // row-sum via ones-fragment (replaces shuffle sum chain)
        ol[r0] = __builtin_amdgcn_mfma_f32_16x16x32_bf16(pa[kk], ones, ol[r0], 0, 0, 0);
      }
    }

    if (havenext) {
      *reinterpret_cast<short8*>(&Ks[cur ^ 1][rr][sc]) = nk0;
      *reinterpret_cast<short8*>(&Ks[cur ^ 1][rr + 32][sc]) = nk1;
      *reinterpret_cast<short8*>(&VTs[cur ^ 1][rr][sc]) = nv0;
      *reinterpret_cast<short8*>(&VTs[cur ^ 1][rr + 32][sc]) = nv1;
    }
    __syncthreads();
    cur ^= 1;
  }

  // epilogue: y[t][h*64+d]
  #pragma unroll
  for (int r0 = 0; r0 < 2; ++r0) {
    const int orow = q0 + w * 32 + r0 * 16 + g * 4;
    const int ocol = h * DH + li;
    #pragma unroll
    for (int db = 0; db < 4; ++db) {
      #pragma unroll
      for (int r = 0; r < 4; ++r) {
        float v = o[r0][db][r] / ol[r0][r];
        y[(orow + r) * Cdim + ocol + db * 16] = f2bf(v);
      }
    }
  }
}

extern "C" void kernel_launch(void* const* d_in, const int* in_sizes, int n_in,
                              void* d_out, int out_size, void* d_ws, size_t ws_size,
                              hipStream_t stream) {
  (void)in_sizes; (void)n_in; (void)out_size; (void)ws_size;
  const float* x  = (const float*)d_in[0];
  const float* wa = (const float*)d_in[1];
  const float* wp = (const float*)d_in[2];
  const int*   nf = (const int*)d_in[3];
  float* out = (float*)d_out;

  char* ws = (char*)d_ws;
  unsigned short* x_bf = (unsigned short*)(ws);                              // 8 MiB
  unsigned short* waT  = (unsigned short*)(ws + (size_t)8  * 1024 * 1024);   // 6 MiB
  unsigned short* wpT  = (unsigned short*)(ws + (size_t)14 * 1024 * 1024);   // 2 MiB
  unsigned short* qkvb = (unsigned short*)(ws + (size_t)16 * 1024 * 1024);   // 24 MiB
  unsigned short* ybf  = (unsigned short*)(ws + (size_t)40 * 1024 * 1024);   // 8 MiB

  cvt_kernel<<<4096, 256, 0, stream>>>(x, x_bf, Tq * Cdim);
  transpose_cvt<<<dim3(48, 16), 256, 0, stream>>>(wa, waT, 1024, 3072);
  transpose_cvt<<<dim3(16, 16), 256, 0, stream>>>(wp, wpT, 1024, 1024);
  gemm_bt<0><<<dim3(24, 32), 256, 0, stream>>>(x_bf, waT, (void*)qkvb, Tq, 3 * Cdim, Cdim);
  attn_kernel<<<NH * (Tq / 128), 256, 0, stream>>>(qkvb, ybf, nf);
  gemm_bt<1><<<dim3(Cdim / 128, Tq / 128), 256, 0, stream>>>(ybf, wpT, (void*)out, Tq, Cdim, Cdim);
}

// Round 4
// 230.646 us; speedup vs baseline: 1.3686x; 1.2971x over previous
//
#include <hip/hip_runtime.h>
#include <hip/hip_bf16.h>

#define Tq 4096
#define Cdim 1024
#define NH 16
#define DH 64

typedef __attribute__((ext_vector_type(8))) short short8;
typedef __attribute__((ext_vector_type(4))) float f32x4;

__device__ __forceinline__ unsigned short f2bf(float f) {
  union { float f; unsigned int u; } v; v.f = f;
  unsigned int r = v.u + 0x7FFFu + ((v.u >> 16) & 1u);
  return (unsigned short)(r >> 16);
}

__device__ __forceinline__ unsigned int cvtpk_bf16(float lo, float hi) {
  unsigned int r;
  asm volatile("v_cvt_pk_bf16_f32 %0, %1, %2" : "=v"(r) : "v"(lo), "v"(hi));
  return r;
}

// ---------------- fp32 -> bf16 convert ----------------
__global__ void cvt_kernel(const float* __restrict__ in, unsigned short* __restrict__ out, int n) {
  int idx = (blockIdx.x * blockDim.x + threadIdx.x) * 4;
  if (idx + 3 < n) {
    float4 v = *reinterpret_cast<const float4*>(in + idx);
    ushort4 o;
    o.x = f2bf(v.x); o.y = f2bf(v.y); o.z = f2bf(v.z); o.w = f2bf(v.w);
    *reinterpret_cast<ushort4*>(out + idx) = o;
  }
}

// ------------- transpose + convert: in[R][C] f32 -> out[C][R] bf16 -------------
__global__ void transpose_cvt(const float* __restrict__ in, unsigned short* __restrict__ out,
                              int R, int Ccols) {
  __shared__ float tile[64][65];
  int c0 = blockIdx.x * 64, r0 = blockIdx.y * 64;
  int tx = threadIdx.x & 63;
  int ty = threadIdx.x >> 6;   // 0..3
  #pragma unroll
  for (int rr = 0; rr < 64; rr += 4)
    tile[rr + ty][tx] = in[(r0 + rr + ty) * Ccols + c0 + tx];
  __syncthreads();
  #pragma unroll
  for (int rr = 0; rr < 64; rr += 4)
    out[(c0 + rr + ty) * R + r0 + tx] = f2bf(tile[tx][rr + ty]);
}

// ------------- GEMM: C[M][N] = A[M][K](bf16) * B^T[N][K](bf16) -------------
template<int OUT_MODE>
__global__ __launch_bounds__(256, 2)
void gemm_bt(const unsigned short* __restrict__ A,
             const unsigned short* __restrict__ B,
             void* __restrict__ Cout,
             int M, int N, int K)
{
  __shared__ __align__(16) unsigned short As[128][72];
  __shared__ __align__(16) unsigned short Bs[128][72];
  const int tid = threadIdx.x;
  const int lane = tid & 63;
  const int wave = tid >> 6;
  const int wm = wave >> 1, wn = wave & 1;
  const int m0 = blockIdx.y * 128, n0 = blockIdx.x * 128;

  f32x4 acc[4][4] = {};

  const int srow = tid >> 3;          // 0..31
  const int scol = (tid & 7) * 8;     // element col

  for (int k0 = 0; k0 < K; k0 += 64) {
    __syncthreads();
    #pragma unroll
    for (int r = 0; r < 128; r += 32) {
      *reinterpret_cast<short8*>(&As[srow + r][scol]) =
        *reinterpret_cast<const short8*>(&A[(m0 + srow + r) * K + k0 + scol]);
      *reinterpret_cast<short8*>(&Bs[srow + r][scol]) =
        *reinterpret_cast<const short8*>(&B[(n0 + srow + r) * K + k0 + scol]);
    }
    __syncthreads();
    #pragma unroll
    for (int kk = 0; kk < 64; kk += 32) {
      const int frow = lane & 15;
      const int fcol = kk + 8 * (lane >> 4);
      short8 a[4], b[4];
      #pragma unroll
      for (int i = 0; i < 4; ++i) {
        a[i] = *reinterpret_cast<const short8*>(&As[wm * 64 + i * 16 + frow][fcol]);
        b[i] = *reinterpret_cast<const short8*>(&Bs[wn * 64 + i * 16 + frow][fcol]);
      }
      #pragma unroll
      for (int i = 0; i < 4; ++i)
        #pragma unroll
        for (int j = 0; j < 4; ++j)
          acc[i][j] = __builtin_amdgcn_mfma_f32_16x16x32_bf16(a[i], b[j], acc[i][j], 0, 0, 0);
    }
  }

  const int rbase = (lane >> 4) * 4;
  const int ccol = lane & 15;
  #pragma unroll
  for (int i = 0; i < 4; ++i) {
    const int row0 = m0 + wm * 64 + i * 16 + rbase;
    #pragma unroll
    for (int j = 0; j < 4; ++j) {
      const int col = n0 + wn * 64 + j * 16 + ccol;
      if (OUT_MODE == 0) {
        unsigned short* q = (unsigned short*)Cout;
        int sec = col >> 10, rem = col & 1023;
        int hh = rem >> 6, d = rem & 63;
        if (sec == 2) {
          ushort4 pk;
          pk.x = f2bf(acc[i][j][0]); pk.y = f2bf(acc[i][j][1]);
          pk.z = f2bf(acc[i][j][2]); pk.w = f2bf(acc[i][j][3]);
          *reinterpret_cast<ushort4*>(
              &q[((size_t)(2 * NH + hh) * DH + d) * Tq + row0]) = pk;
        } else {
          #pragma unroll
          for (int r = 0; r < 4; ++r)
            q[(((size_t)sec * NH + hh) * Tq + row0 + r) * DH + d] = f2bf(acc[i][j][r]);
        }
      } else {
        #pragma unroll
        for (int r = 0; r < 4; ++r)
          ((float*)Cout)[(row0 + r) * N + col] = acc[i][j][r];
      }
    }
  }
}

// ------------- flash attention: causal + dense prefix -------------
// QBLK=128, 8 waves x 16 q-rows, 512 threads, swapped-QK^T in-register softmax.
__global__ __launch_bounds__(512, 4)
void attn_kernel(const unsigned short* __restrict__ qkv,   // Q[h][t][d],K[h][t][d],VT[h][d][t]
                 unsigned short* __restrict__ y,           // [Tq][Cdim] bf16
                 const int* __restrict__ nf_ptr)
{
  __shared__ __align__(16) unsigned short Ks[2][64][72];
  __shared__ __align__(16) unsigned short VTs[2][64][72];

  const int tid  = threadIdx.x;
  const int lane = tid & 63;
  const int w    = tid >> 6;           // 0..7
  const int g    = lane >> 4;          // 0..3
  const int li   = lane & 15;

  const int h  = blockIdx.x & 15;
  const int iq = (blockIdx.x >> 4) & 15;
  const int hi = blockIdx.x >> 8;
  const int qc = hi ? iq : 31 - iq;    // heavy/light pairing across co-resident blocks
  const int q0 = qc * 128;
  const int nf = nf_ptr[0];

  const unsigned short* Qh  = qkv + (size_t)h * Tq * DH;
  const unsigned short* Kh  = qkv + (size_t)(NH + h) * Tq * DH;
  const unsigned short* VTh = qkv + (size_t)(2 * NH + h) * DH * Tq;

  // Q fragments (B-operand of swapped QK^T): col = li = q-row
  const int qrow = q0 + w * 16 + li;
  short8 qf[2];
  #pragma unroll
  for (int kk = 0; kk < 2; ++kk)
    qf[kk] = *reinterpret_cast<const short8*>(&Qh[qrow * DH + kk * 32 + 8 * g]);

  f32x4 o[4] = {};
  f32x4 ol = {};
  float m_r = -1e30f;

  short8 ones;
  #pragma unroll
  for (int e = 0; e < 8; ++e) ones[e] = (short)0x3F80;   // bf16 1.0

  int lastt = q0 + 127;
  if (nf - 1 > lastt) lastt = nf - 1;
  const int ktend = lastt >> 6;

  const float SCL = 0.125f * 1.44269504f;   // 1/sqrt(64) * log2(e)

  const int srow = tid >> 3;          // 0..63
  const int scol = (tid & 7) * 8;

  // prologue: stage tile 0 into buffer 0 (each thread: 1 K seg + 1 V seg)
  *reinterpret_cast<short8*>(&Ks[0][srow][scol]) =
      *reinterpret_cast<const short8*>(&Kh[srow * DH + scol]);
  *reinterpret_cast<short8*>(&VTs[0][srow][scol]) =
      *reinterpret_cast<const short8*>(&VTh[(size_t)srow * Tq + scol]);
  __syncthreads();

  const int srcA4 = (li + 32 * (g & 1)) << 2;   // bpermute byte index
  const int srcB4 = srcA4 + 64;

  int cur = 0;
  for (int kt = 0; kt <= ktend; ++kt) {
    const int kv0 = kt * 64;
    const bool havenext = (kt < ktend);
    short8 nk, nv;
    if (havenext) {
      nk = *reinterpret_cast<const short8*>(&Kh[(kv0 + 64 + srow) * DH + scol]);
      nv = *reinterpret_cast<const short8*>(&VTh[(size_t)srow * Tq + kv0 + 64 + scol]);
    }

    // S^T = K · Q^T  (lane li owns q-row li; rows = kv = nb*16 + 4g + r)
    f32x4 s[4];
    #pragma unroll
    for (int nb = 0; nb < 4; ++nb) {
      f32x4 a = {};
      #pragma unroll
      for (int kk = 0; kk < 2; ++kk) {
        short8 kf = *reinterpret_cast<const short8*>(
            &Ks[cur][nb * 16 + li][kk * 32 + 8 * g]);
        a = __builtin_amdgcn_mfma_f32_16x16x32_bf16(kf, qf[kk], a, 0, 0, 0);
      }
      s[nb] = a;
    }

    // scale + mask (in exp2 domain)
    const bool needmask = !((kv0 + 63 <= q0 + w * 16) || (kv0 + 63 < nf));
    float p[4][4];
    #pragma unroll
    for (int nb = 0; nb < 4; ++nb) {
      #pragma unroll
      for (int r = 0; r < 4; ++r) {
        float v = s[nb][r] * SCL;
        if (needmask) {
          const int kvi = kv0 + nb * 16 + 4 * g + r;
          if (!(kvi <= qrow || kvi < nf)) v = -1e30f;
        }
        p[nb][r] = v;
      }
    }

    // row max: 15 in-lane fmax + 2 cross-group shuffles
    float mx = p[0][0];
    #pragma unroll
    for (int nb = 0; nb < 4; ++nb)
      #pragma unroll
      for (int r = 0; r < 4; ++r)
        mx = fmaxf(mx, p[nb][r]);
    mx = fmaxf(mx, __shfl_xor(mx, 16, 64));
    mx = fmaxf(mx, __shfl_xor(mx, 32, 64));

    // defer-max: rescale only when max grew materially (THR=8 in exp2 units)
    if (!__all(mx <= m_r + 8.0f)) {
      float newm = fmaxf(m_r, mx);
      float alpha = exp2f(m_r - newm);
      m_r = newm;
      #pragma unroll
      for (int db = 0; db < 4; ++db)
        #pragma unroll
        for (int r = 0; r < 4; ++r)
          o[db][r] *= alpha;
      ol[0] *= alpha;
    }

    #pragma unroll
    for (int nb = 0; nb < 4; ++nb)
      #pragma unroll
      for (int r = 0; r < 4; ++r)
        p[nb][r] = exp2f(p[nb][r] - m_r);

    // pack P to bf16 + cross-lane exchange -> PV B-fragments; PV MFMA
    #pragma unroll
    for (int kk = 0; kk < 2; ++kk) {
      unsigned int w0 = cvtpk_bf16(p[2 * kk][0], p[2 * kk][1]);
      unsigned int w1 = cvtpk_bf16(p[2 * kk][2], p[2 * kk][3]);
      unsigned int w2 = cvtpk_bf16(p[2 * kk + 1][0], p[2 * kk + 1][1]);
      unsigned int w3 = cvtpk_bf16(p[2 * kk + 1][2], p[2 * kk + 1][3]);
      int A0 = __builtin_amdgcn_ds_bpermute(srcA4, (int)w0);
      int A2 = __builtin_amdgcn_ds_bpermute(srcA4, (int)w2);
      int A1 = __builtin_amdgcn_ds_bpermute(srcA4, (int)w1);
      int A3 = __builtin_amdgcn_ds_bpermute(srcA4, (int)w3);
      int B0 = __builtin_amdgcn_ds_bpermute(srcB4, (int)w0);
      int B2 = __builtin_amdgcn_ds_bpermute(srcB4, (int)w2);
      int B1 = __builtin_amdgcn_ds_bpermute(srcB4, (int)w1);
      int B3 = __builtin_amdgcn_ds_bpermute(srcB4, (int)w3);
      union { unsigned int u[4]; short8 s8; } W;
      const bool lowg = (g < 2);
      W.u[0] = (unsigned int)(lowg ? A0 : A2);
      W.u[1] = (unsigned int)(lowg ? A1 : A3);
      W.u[2] = (unsigned int)(lowg ? B0 : B2);
      W.u[3] = (unsigned int)(lowg ? B1 : B3);
      #pragma unroll
      for (int db = 0; db < 4; ++db) {
        short8 vb = *reinterpret_cast<const short8*>(
            &VTs[cur][db * 16 + li][kk * 32 + 8 * g]);
        o[db] = __builtin_amdgcn_mfma_f32_16x16x32_bf16(vb, W.s8, o[db], 0, 0, 0);
      }
      ol = __builtin_amdgcn_mfma_f32_16x16x32_bf16(ones, W.s8, ol, 0, 0, 0);
    }

    if (havenext) {
      *reinterpret_cast<short8*>(&Ks[cur ^ 1][srow][scol]) = nk;
      *reinterpret_cast<short8*>(&VTs[cur ^ 1][srow][scol]) = nv;
    }
    __syncthreads();
    cur ^= 1;
  }

  // epilogue: lane li owns q-row qrow; d = db*16 + 4g + r (r contiguous -> ushort4)
  const float inv = 1.0f / ol[0];
  unsigned short* yp = y + (size_t)qrow * Cdim + h * DH;
  #pragma unroll
  for (int db = 0; db < 4; ++db) {
    ushort4 pk;
    pk.x = f2bf(o[db][0] * inv);
    pk.y = f2bf(o[db][1] * inv);
    pk.z = f2bf(o[db][2] * inv);
    pk.w = f2bf(o[db][3] * inv);
    *reinterpret_cast<ushort4*>(&yp[db * 16 + 4 * g]) = pk;
  }
}

extern "C" void kernel_launch(void* const* d_in, const int* in_sizes, int n_in,
                              void* d_out, int out_size, void* d_ws, size_t ws_size,
                              hipStream_t stream) {
  (void)in_sizes; (void)n_in; (void)out_size; (void)ws_size;
  const float* x  = (const float*)d_in[0];
  const float* wa = (const float*)d_in[1];
  const float* wp = (const float*)d_in[2];
  const int*   nf = (const int*)d_in[3];
  float* out = (float*)d_out;

  char* ws = (char*)d_ws;
  unsigned short* x_bf = (unsigned short*)(ws);                              // 8 MiB
  unsigned short* waT  = (unsigned short*)(ws + (size_t)8  * 1024 * 1024);   // 6 MiB
  unsigned short* wpT  = (unsigned short*)(ws + (size_t)14 * 1024 * 1024);   // 2 MiB
  unsigned short* qkvb = (unsigned short*)(ws + (size_t)16 * 1024 * 1024);   // 24 MiB
  unsigned short* ybf  = (unsigned short*)(ws + (size_t)40 * 1024 * 1024);   // 8 MiB

  cvt_kernel<<<4096, 256, 0, stream>>>(x, x_bf, Tq * Cdim);
  transpose_cvt<<<dim3(48, 16), 256, 0, stream>>>(wa, waT, 1024, 3072);
  transpose_cvt<<<dim3(16, 16), 256, 0, stream>>>(wp, wpT, 1024, 1024);
  gemm_bt<0><<<dim3(24, 32), 256, 0, stream>>>(x_bf, waT, (void*)qkvb, Tq, 3 * Cdim, Cdim);
  attn_kernel<<<512, 512, 0, stream>>>(qkvb, ybf, nf);
  gemm_bt<1><<<dim3(Cdim / 128, Tq / 128), 256, 0, stream>>>(ybf, wpT, (void*)out, Tq, Cdim, Cdim);
}

// Round 5
// 165.174 us; speedup vs baseline: 1.9111x; 1.3964x over previous
//
#include <hip/hip_runtime.h>
#include <hip/hip_bf16.h>

#define Tq 4096
#define Cdim 1024
#define NH 16
#define DH 64

typedef __attribute__((ext_vector_type(8))) short short8;
typedef __attribute__((ext_vector_type(4))) float f32x4;

__device__ __forceinline__ unsigned short f2bf(float f) {
  union { float f; unsigned int u; } v; v.f = f;
  unsigned int r = v.u + 0x7FFFu + ((v.u >> 16) & 1u);
  return (unsigned short)(r >> 16);
}

__device__ __forceinline__ unsigned int cvtpk_bf16(float lo, float hi) {
  unsigned int r;
  asm volatile("v_cvt_pk_bf16_f32 %0, %1, %2" : "=v"(r) : "v"(lo), "v"(hi));
  return r;
}

// ---------------- fp32 -> bf16 convert ----------------
__global__ void cvt_kernel(const float* __restrict__ in, unsigned short* __restrict__ out, int n) {
  int idx = (blockIdx.x * blockDim.x + threadIdx.x) * 4;
  if (idx + 3 < n) {
    float4 v = *reinterpret_cast<const float4*>(in + idx);
    ushort4 o;
    o.x = f2bf(v.x); o.y = f2bf(v.y); o.z = f2bf(v.z); o.w = f2bf(v.w);
    *reinterpret_cast<ushort4*>(out + idx) = o;
  }
}

// ------------- transpose + convert: in[R][C] f32 -> out[C][R] bf16 -------------
__global__ void transpose_cvt(const float* __restrict__ in, unsigned short* __restrict__ out,
                              int R, int Ccols) {
  __shared__ float tile[64][65];
  int c0 = blockIdx.x * 64, r0 = blockIdx.y * 64;
  int tx = threadIdx.x & 63;
  int ty = threadIdx.x >> 6;   // 0..3
  #pragma unroll
  for (int rr = 0; rr < 64; rr += 4)
    tile[rr + ty][tx] = in[(r0 + rr + ty) * Ccols + c0 + tx];
  __syncthreads();
  #pragma unroll
  for (int rr = 0; rr < 64; rr += 4)
    out[(c0 + rr + ty) * R + r0 + tx] = f2bf(tile[tx][rr + ty]);
}

// ------------- GEMM: C[M][N] = A[M][K](bf16) * B^T[N][K](bf16) -------------
// m97 structure: linear LDS + global_load_lds width-16, 2 barriers/K-step.
template<int OUT_MODE>
__global__ __launch_bounds__(256, 3)
void gemm_bt(const unsigned short* __restrict__ A,
             const unsigned short* __restrict__ B,
             void* __restrict__ Cout,
             int M, int N, int K)
{
  __shared__ __align__(16) unsigned short As[128][64];
  __shared__ __align__(16) unsigned short Bs[128][64];
  const int tid = threadIdx.x;
  const int lane = tid & 63;
  const int wave = tid >> 6;
  const int wm = wave >> 1, wn = wave & 1;
  const int m0 = blockIdx.y * 128, n0 = blockIdx.x * 128;

  f32x4 acc[4][4] = {};

  const int lrow = lane >> 3;        // 0..7 (row within one 1KB wave deposit)
  const int lcol = (lane & 7) * 8;   // ushort col within 64

  for (int k0 = 0; k0 < K; k0 += 64) {
    __syncthreads();
    #pragma unroll
    for (int t = 0; t < 4; ++t) {
      const int r = wave * 32 + t * 8;
      __builtin_amdgcn_global_load_lds(
        (const __attribute__((address_space(1))) void*)&A[(size_t)(m0 + r + lrow) * K + k0 + lcol],
        (__attribute__((address_space(3))) void*)&As[r][0], 16, 0, 0);
      __builtin_amdgcn_global_load_lds(
        (const __attribute__((address_space(1))) void*)&B[(size_t)(n0 + r + lrow) * K + k0 + lcol],
        (__attribute__((address_space(3))) void*)&Bs[r][0], 16, 0, 0);
    }
    __syncthreads();
    #pragma unroll
    for (int kk = 0; kk < 64; kk += 32) {
      const int frow = lane & 15;
      const int fcol = kk + 8 * (lane >> 4);
      short8 a[4], b[4];
      #pragma unroll
      for (int i = 0; i < 4; ++i) {
        a[i] = *reinterpret_cast<const short8*>(&As[wm * 64 + i * 16 + frow][fcol]);
        b[i] = *reinterpret_cast<const short8*>(&Bs[wn * 64 + i * 16 + frow][fcol]);
      }
      #pragma unroll
      for (int i = 0; i < 4; ++i)
        #pragma unroll
        for (int j = 0; j < 4; ++j)
          acc[i][j] = __builtin_amdgcn_mfma_f32_16x16x32_bf16(a[i], b[j], acc[i][j], 0, 0, 0);
    }
  }

  const int rbase = (lane >> 4) * 4;
  const int ccol = lane & 15;
  #pragma unroll
  for (int i = 0; i < 4; ++i) {
    const int row0 = m0 + wm * 64 + i * 16 + rbase;
    #pragma unroll
    for (int j = 0; j < 4; ++j) {
      const int col = n0 + wn * 64 + j * 16 + ccol;
      if (OUT_MODE == 0) {
        unsigned short* q = (unsigned short*)Cout;
        int sec = col >> 10, rem = col & 1023;
        int hh = rem >> 6, d = rem & 63;
        if (sec == 2) {
          ushort4 pk;
          pk.x = f2bf(acc[i][j][0]); pk.y = f2bf(acc[i][j][1]);
          pk.z = f2bf(acc[i][j][2]); pk.w = f2bf(acc[i][j][3]);
          *reinterpret_cast<ushort4*>(
              &q[((size_t)(2 * NH + hh) * DH + d) * Tq + row0]) = pk;
        } else {
          #pragma unroll
          for (int r = 0; r < 4; ++r)
            q[(((size_t)sec * NH + hh) * Tq + row0 + r) * DH + d] = f2bf(acc[i][j][r]);
        }
      } else {
        #pragma unroll
        for (int r = 0; r < 4; ++r)
          ((float*)Cout)[(row0 + r) * N + col] = acc[i][j][r];
      }
    }
  }
}

// ------------- flash attention: causal + dense prefix -------------
// QBLK=128, 8 waves x 16 q-rows, 512 threads, swapped-QK^T in-register softmax,
// P redistribution via permlane swaps (4x4 word transpose across 16-lane groups).
__global__ __launch_bounds__(512, 4)
void attn_kernel(const unsigned short* __restrict__ qkv,   // Q[h][t][d],K[h][t][d],VT[h][d][t]
                 unsigned short* __restrict__ y,           // [Tq][Cdim] bf16
                 const int* __restrict__ nf_ptr)
{
  __shared__ __align__(16) unsigned short Ks[2][64][72];
  __shared__ __align__(16) unsigned short VTs[2][64][72];

  const int tid  = threadIdx.x;
  const int lane = tid & 63;
  const int w    = tid >> 6;           // 0..7
  const int g    = lane >> 4;          // 0..3
  const int li   = lane & 15;

  const int h  = blockIdx.x & 15;
  const int iq = (blockIdx.x >> 4) & 15;
  const int hi = blockIdx.x >> 8;
  const int qc = hi ? iq : 31 - iq;    // heavy/light pairing across co-resident blocks
  const int q0 = qc * 128;
  const int nf = nf_ptr[0];

  const unsigned short* Qh  = qkv + (size_t)h * Tq * DH;
  const unsigned short* Kh  = qkv + (size_t)(NH + h) * Tq * DH;
  const unsigned short* VTh = qkv + (size_t)(2 * NH + h) * DH * Tq;

  // Q fragments (B-operand of swapped QK^T): col = li = q-row
  const int qrow = q0 + w * 16 + li;
  short8 qf[2];
  #pragma unroll
  for (int kk = 0; kk < 2; ++kk)
    qf[kk] = *reinterpret_cast<const short8*>(&Qh[qrow * DH + kk * 32 + 8 * g]);

  f32x4 o[4] = {};
  f32x4 ol = {};
  float m_r = -1e30f;

  short8 ones;
  #pragma unroll
  for (int e = 0; e < 8; ++e) ones[e] = (short)0x3F80;   // bf16 1.0

  int lastt = q0 + 127;
  if (nf - 1 > lastt) lastt = nf - 1;
  const int ktend = lastt >> 6;

  const float SCL = 0.125f * 1.44269504f;   // 1/sqrt(64) * log2(e)

  const int srow = tid >> 3;          // 0..63
  const int scol = (tid & 7) * 8;

  // prologue: stage tile 0 into buffer 0 (each thread: 1 K seg + 1 V seg)
  *reinterpret_cast<short8*>(&Ks[0][srow][scol]) =
      *reinterpret_cast<const short8*>(&Kh[srow * DH + scol]);
  *reinterpret_cast<short8*>(&VTs[0][srow][scol]) =
      *reinterpret_cast<const short8*>(&VTh[(size_t)srow * Tq + scol]);
  __syncthreads();

  int cur = 0;
  for (int kt = 0; kt <= ktend; ++kt) {
    const int kv0 = kt * 64;
    const bool havenext = (kt < ktend);
    short8 nk, nv;
    if (havenext) {
      nk = *reinterpret_cast<const short8*>(&Kh[(kv0 + 64 + srow) * DH + scol]);
      nv = *reinterpret_cast<const short8*>(&VTh[(size_t)srow * Tq + kv0 + 64 + scol]);
    }

    // S^T = K · Q^T  (lane li owns q-row li; rows = kv = nb*16 + 4g + r)
    f32x4 s[4];
    #pragma unroll
    for (int nb = 0; nb < 4; ++nb) {
      f32x4 a = {};
      #pragma unroll
      for (int kk = 0; kk < 2; ++kk) {
        short8 kf = *reinterpret_cast<const short8*>(
            &Ks[cur][nb * 16 + li][kk * 32 + 8 * g]);
        a = __builtin_amdgcn_mfma_f32_16x16x32_bf16(kf, qf[kk], a, 0, 0, 0);
      }
      s[nb] = a;
    }

    // scale + mask (in exp2 domain)
    const bool needmask = !((kv0 + 63 <= q0 + w * 16) || (kv0 + 63 < nf));
    float p[4][4];
    #pragma unroll
    for (int nb = 0; nb < 4; ++nb) {
      #pragma unroll
      for (int r = 0; r < 4; ++r) {
        float v = s[nb][r] * SCL;
        if (needmask) {
          const int kvi = kv0 + nb * 16 + 4 * g + r;
          if (!(kvi <= qrow || kvi < nf)) v = -1e30f;
        }
        p[nb][r] = v;
      }
    }

    // row max: 15 in-lane fmax + 2 cross-group shuffles
    float mx = p[0][0];
    #pragma unroll
    for (int nb = 0; nb < 4; ++nb)
      #pragma unroll
      for (int r = 0; r < 4; ++r)
        mx = fmaxf(mx, p[nb][r]);
    mx = fmaxf(mx, __shfl_xor(mx, 16, 64));
    mx = fmaxf(mx, __shfl_xor(mx, 32, 64));

    // defer-max: rescale only when max grew materially (THR=8 in exp2 units)
    if (!__all(mx <= m_r + 8.0f)) {
      float newm = fmaxf(m_r, mx);
      float alpha = exp2f(m_r - newm);
      m_r = newm;
      #pragma unroll
      for (int db = 0; db < 4; ++db)
        #pragma unroll
        for (int r = 0; r < 4; ++r)
          o[db][r] *= alpha;
      ol[0] *= alpha;
    }

    #pragma unroll
    for (int nb = 0; nb < 4; ++nb)
      #pragma unroll
      for (int r = 0; r < 4; ++r)
        p[nb][r] = exp2f(p[nb][r] - m_r);

    // pack P to bf16; redistribute to PV B-fragments via 4x4 word transpose:
    // stage A: permlane32_swap pairs (m0,m2),(m1,m3); stage B: permlane16_swap.
    // Verified element-wise identical to the round-4 bpermute scheme.
    #pragma unroll
    for (int kk = 0; kk < 2; ++kk) {
      unsigned int X1 = cvtpk_bf16(p[2 * kk][0], p[2 * kk][1]);       // m0
      unsigned int X2 = cvtpk_bf16(p[2 * kk][2], p[2 * kk][3]);       // m1
      unsigned int Y1 = cvtpk_bf16(p[2 * kk + 1][0], p[2 * kk + 1][1]); // m2
      unsigned int Y2 = cvtpk_bf16(p[2 * kk + 1][2], p[2 * kk + 1][3]); // m3
      asm volatile("v_permlane32_swap_b32 %0, %1" : "+v"(X1), "+v"(Y1));
      asm volatile("v_permlane32_swap_b32 %0, %1" : "+v"(X2), "+v"(Y2));
      asm volatile("v_permlane16_swap_b32 %0, %1" : "+v"(X1), "+v"(Y1));
      asm volatile("v_permlane16_swap_b32 %0, %1" : "+v"(X2), "+v"(Y2));
      union { unsigned int u[4]; short8 s8; } W;
      W.u[0] = X1; W.u[1] = X2; W.u[2] = Y1; W.u[3] = Y2;
      #pragma unroll
      for (int db = 0; db < 4; ++db) {
        short8 vb = *reinterpret_cast<const short8*>(
            &VTs[cur][db * 16 + li][kk * 32 + 8 * g]);
        o[db] = __builtin_amdgcn_mfma_f32_16x16x32_bf16(vb, W.s8, o[db], 0, 0, 0);
      }
      ol = __builtin_amdgcn_mfma_f32_16x16x32_bf16(ones, W.s8, ol, 0, 0, 0);
    }

    if (havenext) {
      *reinterpret_cast<short8*>(&Ks[cur ^ 1][srow][scol]) = nk;
      *reinterpret_cast<short8*>(&VTs[cur ^ 1][srow][scol]) = nv;
    }
    __syncthreads();
    cur ^= 1;
  }

  // epilogue: lane li owns q-row qrow; d = db*16 + 4g + r (r contiguous -> ushort4)
  const float inv = 1.0f / ol[0];
  unsigned short* yp = y + (size_t)qrow * Cdim + h * DH;
  #pragma unroll
  for (int db = 0; db < 4; ++db) {
    ushort4 pk;
    pk.x = f2bf(o[db][0] * inv);
    pk.y = f2bf(o[db][1] * inv);
    pk.z = f2bf(o[db][2] * inv);
    pk.w = f2bf(o[db][3] * inv);
    *reinterpret_cast<ushort4*>(&yp[db * 16 + 4 * g]) = pk;
  }
}

extern "C" void kernel_launch(void* const* d_in, const int* in_sizes, int n_in,
                              void* d_out, int out_size, void* d_ws, size_t ws_size,
                              hipStream_t stream) {
  (void)in_sizes; (void)n_in; (void)out_size; (void)ws_size;
  const float* x  = (const float*)d_in[0];
  const float* wa = (const float*)d_in[1];
  const float* wp = (const float*)d_in[2];
  const int*   nf = (const int*)d_in[3];
  float* out = (float*)d_out;

  char* ws = (char*)d_ws;
  unsigned short* x_bf = (unsigned short*)(ws);                              // 8 MiB
  unsigned short* waT  = (unsigned short*)(ws + (size_t)8  * 1024 * 1024);   // 6 MiB
  unsigned short* wpT  = (unsigned short*)(ws + (size_t)14 * 1024 * 1024);   // 2 MiB
  unsigned short* qkvb = (unsigned short*)(ws + (size_t)16 * 1024 * 1024);   // 24 MiB
  unsigned short* ybf  = (unsigned short*)(ws + (size_t)40 * 1024 * 1024);   // 8 MiB

  cvt_kernel<<<4096, 256, 0, stream>>>(x, x_bf, Tq * Cdim);
  transpose_cvt<<<dim3(48, 16), 256, 0, stream>>>(wa, waT, 1024, 3072);
  transpose_cvt<<<dim3(16, 16), 256, 0, stream>>>(wp, wpT, 1024, 1024);
  gemm_bt<0><<<dim3(24, 32), 256, 0, stream>>>(x_bf, waT, (void*)qkvb, Tq, 3 * Cdim, Cdim);
  attn_kernel<<<512, 512, 0, stream>>>(qkvb, ybf, nf);
  gemm_bt<1><<<dim3(Cdim / 128, Tq / 128), 256, 0, stream>>>(ybf, wpT, (void*)out, Tq, Cdim, Cdim);
}